// Round 12
// baseline (50.886 us; speedup 1.0000x reference)
//
#include <hip/hip_runtime.h>
#include <stdint.h>

#define N_S   4096
#define NTOT  8192
#define D     256
#define NBLK  2080            // 64*65/2 triangular blocks of 128x128
#define PREPB 512             // prep blocks (16 rows each)

typedef __attribute__((ext_vector_type(4))) float f32x4;     // MFMA acc
typedef __attribute__((ext_vector_type(2))) long longx2;     // 16B = 2 fp8 frags

// ---- workspace layout (bytes). Everything rewritten every launch. ----
// [0,4096) is zeroed by one hipMemsetAsync each launch (ctr/sqtot/colsum/acc).
#define WS_CTR       0                // u32 prep last-block counter
#define WS_SQTOT     64               // f64 sum of |x_i|^2
#define WS_COLSUM    128              // 256 f64 column sums (2 KB)
#define WS_ACC       2560             // 128 f64 partial-sum slots (1 KB)
#define WS_SQ        4096             // 8192 f32 (32 KB)
#define WS_COEF      36864            // 1 f32
#define WS_XH        65536            // 2 MB fp8, panel/kt-pair/slot-major

// fp8 layout: for row R (panel p=R>>7, rp=R&127), col c (kt=c>>5, u=(c>>3)&3,
// j=c&7):  byte = (p<<15) + ((kt>>1)<<13) + u*2048 + rp*16 + (kt&1)*8 + j
// => each 128-row panel is a contiguous 32 KB block, LDS-stageable verbatim.

// ---------------------------------------------------------------------------
// prep (+ fused bandwidth tail, fence-free): one pass over X. Produces
// (a) sq[i] = |x_i|^2 exact fp32, (b) atomic f64 column sums + sq total,
// (c) fp8 e4m3 X in the kt-pair layout above.
// 512 blocks x 256 threads (2 blocks/CU); wave handles 4 rows.
// ---------------------------------------------------------------------------
__global__ __launch_bounds__(256) void prep_kernel(
    const float* __restrict__ src, const float* __restrict__ tgt,
    float* __restrict__ sq, double* __restrict__ colsum,
    double* __restrict__ sqtot, float* __restrict__ coef,
    unsigned int* __restrict__ ctr, char* __restrict__ xh)
{
    const int b    = blockIdx.x;
    const int tid  = threadIdx.x;
    const int w    = tid >> 6;
    const int lane = tid & 63;
    const int row0 = b * 16 + w * 4;
    const float* base = (row0 < N_S) ? (src + (size_t)row0 * D)
                                     : (tgt + (size_t)(row0 - N_S) * D);
    const int kt = lane >> 3;            // col k-tile of this lane's 4 cols
    const int u  = (lane >> 1) & 3;      // 8-elem k-slot
    const int qb = (lane & 1) * 4;       // dword within the 8B half-granule
    const uint32_t sub = (((uint32_t)kt >> 1) << 13) + (uint32_t)u * 2048u
                       + ((uint32_t)kt & 1u) * 8u + (uint32_t)qb;

    double ca0 = 0.0, ca1 = 0.0, ca2 = 0.0, ca3 = 0.0;
    double wsq = 0.0;
    for (int r = 0; r < 4; ++r) {
        const int row = row0 + r;
        const float4 v = *(const float4*)(base + (size_t)r * D + lane * 4);
        float s = v.x * v.x + v.y * v.y + v.z * v.z + v.w * v.w;
        ca0 += (double)v.x; ca1 += (double)v.y;
        ca2 += (double)v.z; ca3 += (double)v.w;
        #pragma unroll
        for (int off = 32; off; off >>= 1) s += __shfl_xor(s, off, 64);
        if (lane == 0) sq[row] = s;
        wsq += (double)s;

        int pk = __builtin_amdgcn_cvt_pk_fp8_f32(v.x, v.y, 0, false);
        pk     = __builtin_amdgcn_cvt_pk_fp8_f32(v.z, v.w, pk, true);
        const uint32_t off_b = ((uint32_t)(row >> 7) << 15)
                             + (uint32_t)(row & 127) * 16u + sub;
        *(int*)(xh + off_b) = pk;
    }
    __shared__ double cp[4][256];
    __shared__ double sqw[4];
    cp[w][lane * 4 + 0] = ca0;
    cp[w][lane * 4 + 1] = ca1;
    cp[w][lane * 4 + 2] = ca2;
    cp[w][lane * 4 + 3] = ca3;
    if (lane == 0) sqw[w] = wsq;
    __syncthreads();

    const double cpv = cp[0][tid] + cp[1][tid] + cp[2][tid] + cp[3][tid];
    double old0 = __hip_atomic_fetch_add(&colsum[tid], cpv,
                      __ATOMIC_RELAXED, __HIP_MEMORY_SCOPE_AGENT);
    double old1 = 0.0;
    if (tid == 0)
        old1 = __hip_atomic_fetch_add(sqtot, sqw[0] + sqw[1] + sqw[2] + sqw[3],
                      __ATOMIC_RELAXED, __HIP_MEMORY_SCOPE_AGENT);
    asm volatile("" :: "v"(old0), "v"(old1));          // keep results live
    asm volatile("s_waitcnt vmcnt(0)" ::: "memory");   // our RMWs are ack'd
    __syncthreads();

    __shared__ int lastp;
    if (tid == 0)
        lastp = (__hip_atomic_fetch_add(ctr, 1u,
                   __ATOMIC_RELAXED, __HIP_MEMORY_SCOPE_AGENT)
                 == (unsigned)(PREPB - 1)) ? 1 : 0;
    __syncthreads();
    if (!lastp) return;

    const double cs = __hip_atomic_load(&colsum[tid],
                          __ATOMIC_RELAXED, __HIP_MEMORY_SCOPE_AGENT);
    double v = cs * cs;
    #pragma unroll
    for (int off = 32; off; off >>= 1) v += __shfl_xor(v, off, 64);
    __shared__ double r2[4];
    if (lane == 0) r2[w] = v;
    __syncthreads();
    if (tid == 0) {
        const double s2    = r2[0] + r2[1] + r2[2] + r2[3];   // ||sum_i x_i||^2
        const double sumsq = __hip_atomic_load(sqtot,
                                 __ATOMIC_RELAXED, __HIP_MEMORY_SCOPE_AGENT);
        const double n = (double)NTOT;
        const double bwsum = 2.0 * n * sumsq - 2.0 * s2;      // sum_ij L2_ij
        double bandwidth = bwsum / (n * n - n);
        bandwidth *= 0.25;                                    // / 2^(5//2)
        coef[0] = (float)(-1.4426950408889634 / (bandwidth * 16.0));
    }
}

// ---------------------------------------------------------------------------
// main: triangular 128x128 tiles. B panel LDS-staged (32 KB, 4 blocks/CU);
// A reg-direct from L2 with 1-deep prefetch; launch_bounds(256,4).
// s_setprio(1) around the MFMA cluster (blocks are phase-staggered -> the
// scheduler can prefer MFMA-issuing waves). Horner epilogue + exact-5.0 diag
// fix. Tail: one relaxed f64 atomicAdd into accum[bid&127].
// ---------------------------------------------------------------------------
__global__ __launch_bounds__(256, 4) void mmd_main_kernel(
    const char* __restrict__ xh, const float* __restrict__ sq,
    const float* __restrict__ coef, double* __restrict__ accum)
{
    __shared__ char smem[32768];                    // B panel, whole K, fp8

    const int bid = blockIdx.x;
    const int swz = (bid & 7) * 260 + (bid >> 3);   // bijective XCD swizzle
    int by = (int)((129.0 - sqrt((double)(16641 - 8 * swz))) * 0.5);
    if (by < 0) by = 0;
    while ((by + 1) * 64 - ((by + 1) * by) / 2 <= swz) ++by;
    while (by * 64 - (by * (by - 1)) / 2 > swz) --by;
    const int bx = by + (swz - (by * 64 - (by * (by - 1)) / 2));

    const int tid  = threadIdx.x;
    const int w    = tid >> 6;
    const int lane = tid & 63;
    const int wr   = w >> 1, wc = w & 1;
    const int grp  = lane >> 4;
    const int r16  = lane & 15;

    // ---- stage B panel only (wave w copies bytes [w*8K, w*8K+8K)) ----
    typedef const __attribute__((address_space(1))) void* gp_t;
    typedef __attribute__((address_space(3))) void* lp_t;
    {
        const char* gsrc = xh + ((size_t)bx << 15)
                         + (uint32_t)w * 8192u + (uint32_t)lane * 16u;
        char* ldst = &smem[w * 8192];
        #pragma unroll
        for (int it = 0; it < 8; ++it)
            __builtin_amdgcn_global_load_lds((gp_t)(uintptr_t)(gsrc + it * 1024),
                                             (lp_t)(uintptr_t)(ldst + it * 1024),
                                             16, 0, 0);
    }

    const float negc = coef[0];
    const char* pA = xh + ((size_t)by << 15) + (uint32_t)grp * 2048u
                   + (uint32_t)(wr * 64 + r16) * 16u;
    const uint32_t boff = (uint32_t)grp * 2048u + (uint32_t)(wc * 64 + r16) * 16u;

    f32x4 acc[4][4];
    #pragma unroll
    for (int m = 0; m < 4; ++m)
        #pragma unroll
        for (int n = 0; n < 4; ++n)
            acc[m][n] = (f32x4){0.0f, 0.0f, 0.0f, 0.0f};

    longx2 aC[4], aN[4];
    #pragma unroll
    for (int i = 0; i < 4; ++i)
        aC[i] = *(const longx2*)(pA + (uint32_t)i * 256u);
    __syncthreads();                                // B staged

    #pragma unroll
    for (int pr = 0; pr < 4; ++pr) {                // 4 kt-pairs = K 256
        if (pr < 3) {
            #pragma unroll
            for (int i = 0; i < 4; ++i)             // prefetch next A pair
                aN[i] = *(const longx2*)(pA + (uint32_t)(pr + 1) * 8192u
                                            + (uint32_t)i * 256u);
        }
        longx2 bC[4];
        #pragma unroll
        for (int i = 0; i < 4; ++i)
            bC[i] = *(const longx2*)&smem[boff + (uint32_t)pr * 8192u
                                               + (uint32_t)i * 256u];
        __builtin_amdgcn_s_setprio(1);
        #pragma unroll
        for (int m = 0; m < 4; ++m)
            #pragma unroll
            for (int n = 0; n < 4; ++n) {
                acc[m][n] = __builtin_amdgcn_mfma_f32_16x16x32_fp8_fp8(
                                aC[m].x, bC[n].x, acc[m][n], 0, 0, 0);
                acc[m][n] = __builtin_amdgcn_mfma_f32_16x16x32_fp8_fp8(
                                aC[m].y, bC[n].y, acc[m][n], 0, 0, 0);
            }
        __builtin_amdgcn_s_setprio(0);
        if (pr < 3) {
            #pragma unroll
            for (int i = 0; i < 4; ++i) aC[i] = aN[i];
        }
    }

    // epilogue. C layout: col = lane&15 (B/n side), row = grp*4 + reg (A/m side)
    // Horner: y+y^2+y^4+y^8+y^16 = y*(1+y*(1+y2*(1+y4*(1+y8))))
    const float m2c = -2.0f * negc;
    float kst = 0.0f;
    #pragma unroll
    for (int m = 0; m < 4; ++m) {
        float pas[4];
        #pragma unroll
        for (int r = 0; r < 4; ++r)
            pas[r] = negc * sq[by * 128 + wr * 64 + m * 16 + grp * 4 + r];
        #pragma unroll
        for (int n = 0; n < 4; ++n) {
            const float pb = negc * sq[bx * 128 + wc * 64 + n * 16 + r16];
            #pragma unroll
            for (int r = 0; r < 4; ++r) {
                const float arg = fmaf(m2c, acc[m][n][r], pas[r] + pb);
                const float y  = __builtin_amdgcn_exp2f(arg);
                const float y2 = y * y, y4 = y2 * y2, y8 = y4 * y4;
                const float f  = fmaf(y, fmaf(y2, fmaf(y4, 1.0f + y8, 1.0f), 1.0f), 1.0f);
                kst = fmaf(y, f, kst);
            }
        }
    }
    // diagonal fix-up: true diag has L2=0 -> kernel sum exactly 5.
    if (bx == by && wr == wc && (r16 >> 2) == grp) {
        const int rr = r16 & 3;
        #pragma unroll
        for (int m = 0; m < 4; ++m) {
            const float sqv = sq[by * 128 + wr * 64 + m * 16 + r16];
            const float arg = fmaf(m2c, acc[m][m][rr], 2.0f * negc * sqv);
            const float y  = __builtin_amdgcn_exp2f(arg);
            const float y2 = y * y, y4 = y2 * y2, y8 = y4 * y4;
            const float f  = fmaf(y, fmaf(y2, fmaf(y4, 1.0f + y8, 1.0f), 1.0f), 1.0f);
            kst += 5.0f - y * f;
        }
    }
    #pragma unroll
    for (int off = 32; off; off >>= 1) kst += __shfl_xor(kst, off, 64);
    __shared__ double wpart[4];
    if (lane == 0) wpart[w] = (double)kst;
    __syncthreads();
    if (tid == 0) {
        const double s = wpart[0] + wpart[1] + wpart[2] + wpart[3];
        const double sgn  = ((by < 32) == (bx < 32)) ? 1.0 : -1.0;
        const double mult = (bx > by) ? 2.0 : 1.0;
        __hip_atomic_fetch_add(&accum[bid & 127], s * sgn * mult,
                               __ATOMIC_RELAXED, __HIP_MEMORY_SCOPE_AGENT);
    }
}

// ---------------------------------------------------------------------------
// finalize: one wave sums the 128 accumulator slots -> scalar output.
// ---------------------------------------------------------------------------
__global__ __launch_bounds__(64) void finalize_kernel(
    const double* __restrict__ accum, float* __restrict__ out)
{
    const int lane = threadIdx.x;
    double a = accum[lane] + accum[lane + 64];
    #pragma unroll
    for (int off = 32; off; off >>= 1) a += __shfl_xor(a, off, 64);
    if (lane == 0)
        out[0] = (float)(a / ((double)N_S * (double)N_S));
}

extern "C" void kernel_launch(void* const* d_in, const int* in_sizes, int n_in,
                              void* d_out, int out_size, void* d_ws, size_t ws_size,
                              hipStream_t stream)
{
    const float* src = (const float*)d_in[0];
    const float* tgt = (const float*)d_in[1];
    float* out = (float*)d_out;
    char*  ws  = (char*)d_ws;

    unsigned int* ctr = (unsigned int*)(ws + WS_CTR);
    double* sqtot   = (double*)(ws + WS_SQTOT);
    double* colsum  = (double*)(ws + WS_COLSUM);
    double* accum   = (double*)(ws + WS_ACC);
    float*  sq      = (float*)(ws + WS_SQ);
    float*  coef    = (float*)(ws + WS_COEF);
    char*   xh      = ws + WS_XH;

    // zero ctr/sqtot/colsum/accum in one memset node (replaces init kernel)
    hipMemsetAsync(ws, 0, 4096, stream);
    prep_kernel<<<PREPB, 256, 0, stream>>>(src, tgt, sq, colsum, sqtot, coef, ctr, xh);
    mmd_main_kernel<<<NBLK, 256, 0, stream>>>(xh, sq, coef, accum);
    finalize_kernel<<<1, 64, 0, stream>>>(accum, out);
}

// Round 13
// 42.897 us; speedup vs baseline: 1.1862x; 1.1862x over previous
//
#include <hip/hip_runtime.h>
#include <stdint.h>

#define N_S   4096
#define NTOT  8192
#define D     256
#define NBLK  2080            // 64*65/2 triangular blocks of 128x128
#define PREPB 256             // prep blocks (32 rows each)

typedef __attribute__((ext_vector_type(4))) float f32x4;     // MFMA acc
typedef __attribute__((ext_vector_type(2))) long longx2;     // 16B = 2 fp8 frags

// ---- workspace layout (bytes). Everything rewritten every launch. ----
#define WS_CTR       0                // u32 prep last-block counter
#define WS_SQTOT     64               // f64 sum of |x_i|^2
#define WS_COLSUM    128              // 256 f64 column sums (2 KB)
#define WS_ACC       2560             // 128 f64 partial-sum slots (1 KB)
#define WS_SQ        4096             // 8192 f32 (32 KB)
#define WS_COEF      36864            // 1 f32
#define WS_XH        65536            // 2 MB fp8, panel/kt-pair/slot-major

// fp8 layout: for row R (panel p=R>>7, rp=R&127), col c (kt=c>>5, u=(c>>3)&3,
// j=c&7):  byte = (p<<15) + ((kt>>1)<<13) + u*2048 + rp*16 + (kt&1)*8 + j
// => each 128-row panel is a contiguous 32 KB block, LDS-stageable verbatim.

// ---------------------------------------------------------------------------
// init: zero counters/accumulators (ws is poisoned 0xAA before timing).
// ---------------------------------------------------------------------------
__global__ __launch_bounds__(256) void init_kernel(char* __restrict__ ws)
{
    const int tid = threadIdx.x;
    ((double*)(ws + WS_COLSUM))[tid] = 0.0;
    if (tid < 128) ((double*)(ws + WS_ACC))[tid] = 0.0;
    if (tid == 0) {
        *(unsigned int*)(ws + WS_CTR) = 0u;
        *(double*)(ws + WS_SQTOT)     = 0.0;
    }
}

// ---------------------------------------------------------------------------
// prep (+ fused bandwidth tail, fence-free): one pass over X. Produces
// (a) sq[i] = |x_i|^2 exact fp32, (b) atomic f64 column sums + sq total,
// (c) fp8 e4m3 X in the kt-pair layout above.  (identical to R9/R11 - proven)
// ---------------------------------------------------------------------------
__global__ __launch_bounds__(256) void prep_kernel(
    const float* __restrict__ src, const float* __restrict__ tgt,
    float* __restrict__ sq, double* __restrict__ colsum,
    double* __restrict__ sqtot, float* __restrict__ coef,
    unsigned int* __restrict__ ctr, char* __restrict__ xh)
{
    const int b    = blockIdx.x;
    const int tid  = threadIdx.x;
    const int w    = tid >> 6;
    const int lane = tid & 63;
    const int row0 = b * 32 + w * 8;
    const float* base = (row0 < N_S) ? (src + (size_t)row0 * D)
                                     : (tgt + (size_t)(row0 - N_S) * D);
    const int kt = lane >> 3;            // col k-tile of this lane's 4 cols
    const int u  = (lane >> 1) & 3;      // 8-elem k-slot
    const int qb = (lane & 1) * 4;       // dword within the 8B half-granule
    const uint32_t sub = (((uint32_t)kt >> 1) << 13) + (uint32_t)u * 2048u
                       + ((uint32_t)kt & 1u) * 8u + (uint32_t)qb;

    double ca0 = 0.0, ca1 = 0.0, ca2 = 0.0, ca3 = 0.0;
    double wsq = 0.0;
    for (int r = 0; r < 8; ++r) {
        const int row = row0 + r;
        const float4 v = *(const float4*)(base + (size_t)r * D + lane * 4);
        float s = v.x * v.x + v.y * v.y + v.z * v.z + v.w * v.w;
        ca0 += (double)v.x; ca1 += (double)v.y;
        ca2 += (double)v.z; ca3 += (double)v.w;
        #pragma unroll
        for (int off = 32; off; off >>= 1) s += __shfl_xor(s, off, 64);
        if (lane == 0) sq[row] = s;
        wsq += (double)s;

        int pk = __builtin_amdgcn_cvt_pk_fp8_f32(v.x, v.y, 0, false);
        pk     = __builtin_amdgcn_cvt_pk_fp8_f32(v.z, v.w, pk, true);
        const uint32_t off_b = ((uint32_t)(row >> 7) << 15)
                             + (uint32_t)(row & 127) * 16u + sub;
        *(int*)(xh + off_b) = pk;
    }
    __shared__ double cp[4][256];
    __shared__ double sqw[4];
    cp[w][lane * 4 + 0] = ca0;
    cp[w][lane * 4 + 1] = ca1;
    cp[w][lane * 4 + 2] = ca2;
    cp[w][lane * 4 + 3] = ca3;
    if (lane == 0) sqw[w] = wsq;
    __syncthreads();

    const double cpv = cp[0][tid] + cp[1][tid] + cp[2][tid] + cp[3][tid];
    double old0 = __hip_atomic_fetch_add(&colsum[tid], cpv,
                      __ATOMIC_RELAXED, __HIP_MEMORY_SCOPE_AGENT);
    double old1 = 0.0;
    if (tid == 0)
        old1 = __hip_atomic_fetch_add(sqtot, sqw[0] + sqw[1] + sqw[2] + sqw[3],
                      __ATOMIC_RELAXED, __HIP_MEMORY_SCOPE_AGENT);
    asm volatile("" :: "v"(old0), "v"(old1));          // keep results live
    asm volatile("s_waitcnt vmcnt(0)" ::: "memory");   // our RMWs are ack'd
    __syncthreads();

    __shared__ int lastp;
    if (tid == 0)
        lastp = (__hip_atomic_fetch_add(ctr, 1u,
                   __ATOMIC_RELAXED, __HIP_MEMORY_SCOPE_AGENT)
                 == (unsigned)(PREPB - 1)) ? 1 : 0;
    __syncthreads();
    if (!lastp) return;

    const double cs = __hip_atomic_load(&colsum[tid],
                          __ATOMIC_RELAXED, __HIP_MEMORY_SCOPE_AGENT);
    double v = cs * cs;
    #pragma unroll
    for (int off = 32; off; off >>= 1) v += __shfl_xor(v, off, 64);
    __shared__ double r2[4];
    if (lane == 0) r2[w] = v;
    __syncthreads();
    if (tid == 0) {
        const double s2    = r2[0] + r2[1] + r2[2] + r2[3];   // ||sum_i x_i||^2
        const double sumsq = __hip_atomic_load(sqtot,
                                 __ATOMIC_RELAXED, __HIP_MEMORY_SCOPE_AGENT);
        const double n = (double)NTOT;
        const double bwsum = 2.0 * n * sumsq - 2.0 * s2;      // sum_ij L2_ij
        double bandwidth = bwsum / (n * n - n);
        bandwidth *= 0.25;                                    // / 2^(5//2)
        coef[0] = (float)(-1.4426950408889634 / (bandwidth * 16.0));
    }
}

// ---------------------------------------------------------------------------
// main: triangular 128x128 tiles. B panel LDS-staged (32 KB -> 4 blocks/CU);
// A reg-direct from L2 with 1-deep prefetch; launch_bounds(256,4). Horner
// epilogue + exact-5.0 diagonal fix. One relaxed f64 atomicAdd per block.
// (identical to R11 - session best, 43.5 us)
// ---------------------------------------------------------------------------
__global__ __launch_bounds__(256, 4) void mmd_main_kernel(
    const char* __restrict__ xh, const float* __restrict__ sq,
    const float* __restrict__ coef, double* __restrict__ accum)
{
    __shared__ char smem[32768];                    // B panel, whole K, fp8

    const int bid = blockIdx.x;
    const int swz = (bid & 7) * 260 + (bid >> 3);   // bijective XCD swizzle
    int by = (int)((129.0 - sqrt((double)(16641 - 8 * swz))) * 0.5);
    if (by < 0) by = 0;
    while ((by + 1) * 64 - ((by + 1) * by) / 2 <= swz) ++by;
    while (by * 64 - (by * (by - 1)) / 2 > swz) --by;
    const int bx = by + (swz - (by * 64 - (by * (by - 1)) / 2));

    const int tid  = threadIdx.x;
    const int w    = tid >> 6;
    const int lane = tid & 63;
    const int wr   = w >> 1, wc = w & 1;
    const int grp  = lane >> 4;
    const int r16  = lane & 15;

    // ---- stage B panel only (wave w copies bytes [w*8K, w*8K+8K)) ----
    typedef const __attribute__((address_space(1))) void* gp_t;
    typedef __attribute__((address_space(3))) void* lp_t;
    {
        const char* gsrc = xh + ((size_t)bx << 15)
                         + (uint32_t)w * 8192u + (uint32_t)lane * 16u;
        char* ldst = &smem[w * 8192];
        #pragma unroll
        for (int it = 0; it < 8; ++it)
            __builtin_amdgcn_global_load_lds((gp_t)(uintptr_t)(gsrc + it * 1024),
                                             (lp_t)(uintptr_t)(ldst + it * 1024),
                                             16, 0, 0);
    }

    const float negc = coef[0];
    const char* pA = xh + ((size_t)by << 15) + (uint32_t)grp * 2048u
                   + (uint32_t)(wr * 64 + r16) * 16u;
    const uint32_t boff = (uint32_t)grp * 2048u + (uint32_t)(wc * 64 + r16) * 16u;

    f32x4 acc[4][4];
    #pragma unroll
    for (int m = 0; m < 4; ++m)
        #pragma unroll
        for (int n = 0; n < 4; ++n)
            acc[m][n] = (f32x4){0.0f, 0.0f, 0.0f, 0.0f};

    longx2 aC[4], aN[4];
    #pragma unroll
    for (int i = 0; i < 4; ++i)
        aC[i] = *(const longx2*)(pA + (uint32_t)i * 256u);
    __syncthreads();                                // B staged

    #pragma unroll
    for (int pr = 0; pr < 4; ++pr) {                // 4 kt-pairs = K 256
        if (pr < 3) {
            #pragma unroll
            for (int i = 0; i < 4; ++i)             // prefetch next A pair
                aN[i] = *(const longx2*)(pA + (uint32_t)(pr + 1) * 8192u
                                            + (uint32_t)i * 256u);
        }
        longx2 bC[4];
        #pragma unroll
        for (int i = 0; i < 4; ++i)
            bC[i] = *(const longx2*)&smem[boff + (uint32_t)pr * 8192u
                                               + (uint32_t)i * 256u];
        #pragma unroll
        for (int m = 0; m < 4; ++m)
            #pragma unroll
            for (int n = 0; n < 4; ++n) {
                acc[m][n] = __builtin_amdgcn_mfma_f32_16x16x32_fp8_fp8(
                                aC[m].x, bC[n].x, acc[m][n], 0, 0, 0);
                acc[m][n] = __builtin_amdgcn_mfma_f32_16x16x32_fp8_fp8(
                                aC[m].y, bC[n].y, acc[m][n], 0, 0, 0);
            }
        if (pr < 3) {
            #pragma unroll
            for (int i = 0; i < 4; ++i) aC[i] = aN[i];
        }
    }

    // epilogue. C layout: col = lane&15 (B/n side), row = grp*4 + reg (A/m side)
    // Horner: y+y^2+y^4+y^8+y^16 = y*(1+y*(1+y2*(1+y4*(1+y8))))
    const float m2c = -2.0f * negc;
    float kst = 0.0f;
    #pragma unroll
    for (int m = 0; m < 4; ++m) {
        float pas[4];
        #pragma unroll
        for (int r = 0; r < 4; ++r)
            pas[r] = negc * sq[by * 128 + wr * 64 + m * 16 + grp * 4 + r];
        #pragma unroll
        for (int n = 0; n < 4; ++n) {
            const float pb = negc * sq[bx * 128 + wc * 64 + n * 16 + r16];
            #pragma unroll
            for (int r = 0; r < 4; ++r) {
                const float arg = fmaf(m2c, acc[m][n][r], pas[r] + pb);
                const float y  = __builtin_amdgcn_exp2f(arg);
                const float y2 = y * y, y4 = y2 * y2, y8 = y4 * y4;
                const float f  = fmaf(y, fmaf(y2, fmaf(y4, 1.0f + y8, 1.0f), 1.0f), 1.0f);
                kst = fmaf(y, f, kst);
            }
        }
    }
    // diagonal fix-up: true diag has L2=0 -> kernel sum exactly 5.
    if (bx == by && wr == wc && (r16 >> 2) == grp) {
        const int rr = r16 & 3;
        #pragma unroll
        for (int m = 0; m < 4; ++m) {
            const float sqv = sq[by * 128 + wr * 64 + m * 16 + r16];
            const float arg = fmaf(m2c, acc[m][m][rr], 2.0f * negc * sqv);
            const float y  = __builtin_amdgcn_exp2f(arg);
            const float y2 = y * y, y4 = y2 * y2, y8 = y4 * y4;
            const float f  = fmaf(y, fmaf(y2, fmaf(y4, 1.0f + y8, 1.0f), 1.0f), 1.0f);
            kst += 5.0f - y * f;
        }
    }
    #pragma unroll
    for (int off = 32; off; off >>= 1) kst += __shfl_xor(kst, off, 64);
    __shared__ double wpart[4];
    if (lane == 0) wpart[w] = (double)kst;
    __syncthreads();
    if (tid == 0) {
        const double s = wpart[0] + wpart[1] + wpart[2] + wpart[3];
        const double sgn  = ((by < 32) == (bx < 32)) ? 1.0 : -1.0;
        const double mult = (bx > by) ? 2.0 : 1.0;
        __hip_atomic_fetch_add(&accum[bid & 127], s * sgn * mult,
                               __ATOMIC_RELAXED, __HIP_MEMORY_SCOPE_AGENT);
    }
}

// ---------------------------------------------------------------------------
// finalize: one wave sums the 128 accumulator slots -> scalar output.
// ---------------------------------------------------------------------------
__global__ __launch_bounds__(64) void finalize_kernel(
    const double* __restrict__ accum, float* __restrict__ out)
{
    const int lane = threadIdx.x;
    double a = accum[lane] + accum[lane + 64];
    #pragma unroll
    for (int off = 32; off; off >>= 1) a += __shfl_xor(a, off, 64);
    if (lane == 0)
        out[0] = (float)(a / ((double)N_S * (double)N_S));
}

extern "C" void kernel_launch(void* const* d_in, const int* in_sizes, int n_in,
                              void* d_out, int out_size, void* d_ws, size_t ws_size,
                              hipStream_t stream)
{
    const float* src = (const float*)d_in[0];
    const float* tgt = (const float*)d_in[1];
    float* out = (float*)d_out;
    char*  ws  = (char*)d_ws;

    unsigned int* ctr = (unsigned int*)(ws + WS_CTR);
    double* sqtot   = (double*)(ws + WS_SQTOT);
    double* colsum  = (double*)(ws + WS_COLSUM);
    double* accum   = (double*)(ws + WS_ACC);
    float*  sq      = (float*)(ws + WS_SQ);
    float*  coef    = (float*)(ws + WS_COEF);
    char*   xh      = ws + WS_XH;

    init_kernel<<<1, 256, 0, stream>>>(ws);
    prep_kernel<<<PREPB, 256, 0, stream>>>(src, tgt, sq, colsum, sqtot, coef, ctr, xh);
    mmd_main_kernel<<<NBLK, 256, 0, stream>>>(xh, sq, coef, accum);
    finalize_kernel<<<1, 64, 0, stream>>>(accum, out);
}